// Round 9
// baseline (420.719 us; speedup 1.0000x reference)
//
#include <hip/hip_runtime.h>
#include <math.h>

#define DIM 1024
#define NQ 10
#define NL 4
#define SEQ 512
#define NROWS 4096
#define PRED 96

typedef unsigned short ushort_t;
typedef unsigned int uint_t;
using half8   = __attribute__((ext_vector_type(8))) _Float16;
using float4v = __attribute__((ext_vector_type(4))) float;

__device__ inline ushort_t f2h(float f) { _Float16 h = (_Float16)f; return *(ushort_t*)&h; }
__device__ inline uint_t pkh(float a, float b) {
    _Float16 ha = (_Float16)a, hb = (_Float16)b;   // RTE v_cvt_f16_f32
    return (uint_t)(*(ushort_t*)&ha) | ((uint_t)(*(ushort_t*)&hb) << 16);
}

// ---------------------------------------------------------------------------
// MEASUREMENT ROUND: pipeline is verbatim R8 (passed, absmax 9.766e-4).
// Every kernel is a pure function of its inputs, so each dispatch is
// replicated REPS x to separate fixed harness overhead F from kernel sum S:
//   dur9 = F + REPS*S   vs   R8: 114.64 = F + S.
// ---------------------------------------------------------------------------
#define REPS 8

// ---------------------------------------------------------------------------
// Kernel 0: x (fp32) -> xh (f16), same layout. (Verbatim R8/R4, passed.)
// ---------------------------------------------------------------------------
__global__ __launch_bounds__(256)
void convert_x_kernel(const float* __restrict__ x, ushort_t* __restrict__ xh)
{
    int i = (blockIdx.x * 256 + threadIdx.x) * 8;
    float4 a = *(const float4*)(x + i);
    float4 b = *(const float4*)(x + i + 4);
    uint4 o;
    o.x = pkh(a.x, a.y); o.y = pkh(a.z, a.w);
    o.z = pkh(b.x, b.y); o.w = pkh(b.z, b.w);
    *(uint4*)(xh + i) = o;
}

// ---------------------------------------------------------------------------
// Kernel 1: circuit on 512 columns of W_in + bias column. (Verbatim R8/R3.)
// ---------------------------------------------------------------------------
__global__ __launch_bounds__(512)
void circuit_cols_kernel(const float* __restrict__ Wi, const float* __restrict__ b_in,
                         const float* __restrict__ qw,
                         ushort_t* __restrict__ Crt_r, ushort_t* __restrict__ Crt_i,
                         float* __restrict__ dr, float* __restrict__ di)
{
    __shared__ float2 psi[DIM];
    __shared__ float gm[NL * NQ][8];

    const int tid = threadIdx.x;
    const int j = blockIdx.x;

    if (tid < NL * NQ) {
        float phi = qw[tid * 3 + 0], theta = qw[tid * 3 + 1], omega = qw[tid * 3 + 2];
        float ch = cosf(theta * 0.5f), sh = sinf(theta * 0.5f);
        float a = 0.5f * (phi + omega), b = 0.5f * (phi - omega);
        float ca = cosf(a), sa = sinf(a);
        float cb = cosf(b), sb = sinf(b);
        gm[tid][0] =  ch * ca;  gm[tid][1] = -ch * sa;   // m00
        gm[tid][2] = -sh * cb;  gm[tid][3] = -sh * sb;   // m01
        gm[tid][4] =  sh * cb;  gm[tid][5] = -sh * sb;   // m10
        gm[tid][6] =  ch * ca;  gm[tid][7] =  ch * sa;   // m11
    }

    float v0, v1;
    if (j < SEQ) {
        v0 = Wi[(size_t)(2 * tid) * SEQ + j];
        v1 = Wi[(size_t)(2 * tid + 1) * SEQ + j];
    } else {
        v0 = b_in[2 * tid] + 1e-6f;
        v1 = b_in[2 * tid + 1] + 1e-6f;
    }
    psi[2 * tid]     = make_float2(v0, 0.f);
    psi[2 * tid + 1] = make_float2(v1, 0.f);
    __syncthreads();

    for (int l = 0; l < NL; ++l) {
#pragma unroll
        for (int w = 0; w < NQ; ++w) {
            const float* m = gm[l * NQ + w];
            float m00r = m[0], m00i = m[1], m01r = m[2], m01i = m[3];
            float m10r = m[4], m10i = m[5], m11r = m[6], m11i = m[7];
            int mask = 1 << (9 - w);
            int lo = tid & (mask - 1);
            int s0 = ((tid ^ lo) << 1) | lo;
            int s1 = s0 | mask;
            float2 a0 = psi[s0], a1 = psi[s1];
            float2 n0, n1;
            n0.x = m00r * a0.x - m00i * a0.y + m01r * a1.x - m01i * a1.y;
            n0.y = m00r * a0.y + m00i * a0.x + m01r * a1.y + m01i * a1.x;
            n1.x = m10r * a0.x - m10i * a0.y + m11r * a1.x - m11i * a1.y;
            n1.y = m10r * a0.y + m10i * a0.x + m11r * a1.y + m11i * a1.x;
            psi[s0] = n0; psi[s1] = n1;
            __syncthreads();
        }
        int r = l % (NQ - 1) + 1;
        int p0 = tid, p1 = tid + 512;
#pragma unroll
        for (int c = 9; c >= 0; --c) {
            int t = (c + r) % NQ;
            p0 ^= ((p0 >> (9 - c)) & 1) << (9 - t);
            p1 ^= ((p1 >> (9 - c)) & 1) << (9 - t);
        }
        float2 t0 = psi[p0], t1 = psi[p1];
        __syncthreads();
        psi[tid] = t0; psi[tid + 512] = t1;
        __syncthreads();
    }

    float2 o0 = psi[tid], o1 = psi[tid + 512];
    if (j < SEQ) {
        Crt_r[(size_t)tid * SEQ + j]         = f2h(o0.x);
        Crt_i[(size_t)tid * SEQ + j]         = f2h(o0.y);
        Crt_r[(size_t)(tid + 512) * SEQ + j] = f2h(o1.x);
        Crt_i[(size_t)(tid + 512) * SEQ + j] = f2h(o1.y);
    } else {
        dr[tid] = o0.x;        di[tid] = o0.y;
        dr[tid + 512] = o1.x;  di[tid + 512] = o1.y;
    }
}

// ---------------------------------------------------------------------------
// Kernel 2: fused f16-MFMA GEMM + probs + signed partials. (Verbatim R8.)
// ---------------------------------------------------------------------------
#define GBM 128
#define GBNC 64
#define GBK 32
#define LDA 40   // half stride for LDS tiles
#define LDP 65   // float stride for probs tile

__global__ __launch_bounds__(256)
void gemm_fused_kernel(const ushort_t* __restrict__ xh,
                       const ushort_t* __restrict__ Crt_r, const ushort_t* __restrict__ Crt_i,
                       const float* __restrict__ dr, const float* __restrict__ di,
                       float* __restrict__ part)
{
    __shared__ __align__(16) char lds[GBM * LDP * 4];  // 33280 B (probs tile is max)
    ushort_t* Ash = (ushort_t*)lds;            // 128*40 halves = 10240 B
    ushort_t* Bsr = Ash + GBM * LDA;           // 64*40 = 5120 B
    ushort_t* Bsi = Bsr + GBNC * LDA;          // 64*40 = 5120 B
    float*    Ps  = (float*)lds;               // reused after K-loop
    __shared__ float drs[GBNC], dis[GBNC];

    const int tid = threadIdx.x;
    const int bm = blockIdx.x, bn = blockIdx.y;
    const int lane = tid & 63, wv = tid >> 6;
    const int n0 = bn * GBNC;

    if (tid < GBNC) { drs[tid] = dr[n0 + tid]; dis[tid] = di[n0 + tid]; }

    float4v accr[2][4], acci[2][4];
#pragma unroll
    for (int a = 0; a < 2; ++a)
#pragma unroll
        for (int b = 0; b < 4; ++b) { accr[a][b] = (float4v)0.f; acci[a][b] = (float4v)0.f; }

    const int sr = tid >> 1, ko = (tid & 1) * 16;
    const ushort_t* xa = xh + (size_t)(bm * GBM + sr) * SEQ + ko;
    const int bsel = tid >> 7;
    const int nr = (tid & 127) >> 1;
    const int bko = (tid & 1) * 16;
    const ushort_t* bsrc = (bsel ? Crt_i : Crt_r) + (size_t)(n0 + nr) * SEQ + bko;
    ushort_t* bdst = (bsel ? Bsi : Bsr) + nr * LDA + bko;

    const int fm = lane & 15, kq = (lane >> 4) * 8;
    const int wrow = wv * 32;

    for (int k0 = 0; k0 < SEQ; k0 += GBK) {
        uint4 a0 = *(const uint4*)(xa + k0);
        uint4 a1 = *(const uint4*)(xa + k0 + 8);
        *(uint4*)(Ash + sr * LDA + ko)     = a0;
        *(uint4*)(Ash + sr * LDA + ko + 8) = a1;
        uint4 b0 = *(const uint4*)(bsrc + k0);
        uint4 b1 = *(const uint4*)(bsrc + k0 + 8);
        *(uint4*)bdst       = b0;
        *(uint4*)(bdst + 8) = b1;
        __syncthreads();

        half8 ah0 = *(half8*)(Ash + (wrow + fm) * LDA + kq);
        half8 ah1 = *(half8*)(Ash + (wrow + 16 + fm) * LDA + kq);
#pragma unroll
        for (int nt = 0; nt < 4; ++nt) {
            half8 br = *(half8*)(Bsr + (nt * 16 + fm) * LDA + kq);
            half8 bi = *(half8*)(Bsi + (nt * 16 + fm) * LDA + kq);
            accr[0][nt] = __builtin_amdgcn_mfma_f32_16x16x32_f16(ah0, br, accr[0][nt], 0, 0, 0);
            accr[1][nt] = __builtin_amdgcn_mfma_f32_16x16x32_f16(ah1, br, accr[1][nt], 0, 0, 0);
            acci[0][nt] = __builtin_amdgcn_mfma_f32_16x16x32_f16(ah0, bi, acci[0][nt], 0, 0, 0);
            acci[1][nt] = __builtin_amdgcn_mfma_f32_16x16x32_f16(ah1, bi, acci[1][nt], 0, 0, 0);
        }
        __syncthreads();
    }

    const int rq = (lane >> 4) * 4;
#pragma unroll
    for (int mt = 0; mt < 2; ++mt)
#pragma unroll
        for (int nt = 0; nt < 4; ++nt) {
            float drv = drs[nt * 16 + fm], div = dis[nt * 16 + fm];
#pragma unroll
            for (int reg = 0; reg < 4; ++reg) {
                int lrow = wrow + mt * 16 + rq + reg;
                float zr = accr[mt][nt][reg] + drv;
                float zi = acci[mt][nt][reg] + div;
                Ps[lrow * LDP + nt * 16 + fm] = zr * zr + zi * zi;
            }
        }
    __syncthreads();

    {
        const int row = tid >> 1, hh = tid & 1;
        const float* pr = Ps + row * LDP + hh * 32;
        float nrm = 0.f, e0 = 0.f, e1 = 0.f, e2 = 0.f, e3 = 0.f, e4 = 0.f, e5 = 0.f;
#pragma unroll
        for (int i = 0; i < 32; ++i) {
            float p = pr[i];
            int c = hh * 32 + i;
            nrm += p;
            e0 += ((c >> 5) & 1) ? -p : p;   // k=4
            e1 += ((c >> 4) & 1) ? -p : p;   // k=5
            e2 += ((c >> 3) & 1) ? -p : p;   // k=6
            e3 += ((c >> 2) & 1) ? -p : p;   // k=7
            e4 += ((c >> 1) & 1) ? -p : p;   // k=8
            e5 += (c & 1) ? -p : p;          // k=9
        }
        size_t base = ((size_t)(bm * GBM + row) * 32 + (bn * 2 + hh)) * 8;
        part[base + 0] = nrm;
        part[base + 1] = e0; part[base + 2] = e1; part[base + 3] = e2;
        part[base + 4] = e3; part[base + 5] = e4; part[base + 6] = e5;
    }
}

// ---------------------------------------------------------------------------
// Kernel 3: per-row combine + W_out epilogue. (Verbatim R8/R3.)
// ---------------------------------------------------------------------------
__global__ __launch_bounds__(128)
void finalize_kernel(const float* __restrict__ part, const float* __restrict__ W_out,
                     const float* __restrict__ b_out, float* __restrict__ out)
{
    __shared__ float evf[16];
    const int row = blockIdx.x, tid = threadIdx.x;

    if (tid < 64) {
        float v[11];
        if (tid < 32) {
            const float* p = part + ((size_t)row * 32 + tid) * 8;
            float4 a = *(const float4*)p;
            float4 b = *(const float4*)(p + 4);
            float nrm = a.x;
            int bnn = tid >> 1;   // s bits 9..6 = bits 3..0 of bnn
            v[0] = nrm;
            v[1] = (bnn & 8) ? -nrm : nrm;
            v[2] = (bnn & 4) ? -nrm : nrm;
            v[3] = (bnn & 2) ? -nrm : nrm;
            v[4] = (bnn & 1) ? -nrm : nrm;
            v[5] = a.y; v[6] = a.z; v[7] = a.w;
            v[8] = b.x; v[9] = b.y; v[10] = b.z;
        } else {
#pragma unroll
            for (int k = 0; k < 11; ++k) v[k] = 0.f;
        }
#pragma unroll
        for (int m = 16; m; m >>= 1)
#pragma unroll
            for (int k = 0; k < 11; ++k) v[k] += __shfl_xor(v[k], m, 64);
        if (tid == 0) {
            float inv = 1.0f / v[0];
#pragma unroll
            for (int k = 0; k < 10; ++k) evf[k] = v[k + 1] * inv;
        }
    }
    __syncthreads();
    if (tid < PRED) {
        float o = b_out[tid];
#pragma unroll
        for (int k = 0; k < NQ; ++k) o = fmaf(W_out[tid * NQ + k], evf[k], o);
        out[(size_t)row * PRED + tid] = o;
    }
}

extern "C" void kernel_launch(void* const* d_in, const int* in_sizes, int n_in,
                              void* d_out, int out_size, void* d_ws, size_t ws_size,
                              hipStream_t stream) {
    const float* x     = (const float*)d_in[0];
    const float* W_in  = (const float*)d_in[1];
    const float* b_in  = (const float*)d_in[2];
    const float* qw    = (const float*)d_in[3];
    const float* W_out = (const float*)d_in[4];
    const float* b_out = (const float*)d_in[5];
    float* out = (float*)d_out;

    char* w = (char*)d_ws;
    const size_t MB = 1u << 20;
    ushort_t* xh    = (ushort_t*)w;               // 4 MB  f16 x
    ushort_t* Crt_r = (ushort_t*)(w + 4 * MB);    // 1 MB  [s][j]
    ushort_t* Crt_i = (ushort_t*)(w + 5 * MB);    // 1 MB
    float*    dr    = (float*)(w + 6 * MB);       // 4 KB
    float*    di    = dr + DIM;                   // 4 KB
    float*    part  = (float*)(w + 7 * MB);       // 4 MB

    // Measurement: REPS x each idempotent stage (output bitwise identical).
    for (int r = 0; r < REPS; ++r)
        convert_x_kernel<<<NROWS * SEQ / (256 * 8), 256, 0, stream>>>(x, xh);
    for (int r = 0; r < REPS; ++r)
        circuit_cols_kernel<<<SEQ + 1, 512, 0, stream>>>(W_in, b_in, qw, Crt_r, Crt_i, dr, di);
    dim3 g2(NROWS / GBM, DIM / GBNC);
    for (int r = 0; r < REPS; ++r)
        gemm_fused_kernel<<<g2, 256, 0, stream>>>(xh, Crt_r, Crt_i, dr, di, part);
    for (int r = 0; r < REPS; ++r)
        finalize_kernel<<<NROWS, 128, 0, stream>>>(part, W_out, b_out, out);
}

// Round 11
// 130.686 us; speedup vs baseline: 3.2193x; 3.2193x over previous
//
#include <hip/hip_runtime.h>
#include <math.h>

#define DIM 1024
#define NQ 10
#define NL 4
#define SEQ 512
#define NROWS 4096
#define PRED 96

typedef unsigned short ushort_t;
typedef unsigned int uint_t;
using half8   = __attribute__((ext_vector_type(8))) _Float16;
using float4v = __attribute__((ext_vector_type(4))) float;

__device__ inline ushort_t f2h(float f) { _Float16 h = (_Float16)f; return *(ushort_t*)&h; }
__device__ inline uint_t pkh(float a, float b) {
    _Float16 ha = (_Float16)a, hb = (_Float16)b;   // RTE v_cvt_f16_f32
    return (uint_t)(*(ushort_t*)&ha) | ((uint_t)(*(ushort_t*)&hb) << 16);
}

// XOR-ladder layer permutation (GF(2)-linear). Verified R1-R5.
__device__ inline int permf(int s, int r) {
#pragma unroll
    for (int c = 9; c >= 0; --c) {
        int t = (c + r) % 10;
        s ^= ((s >> (9 - c)) & 1) << (9 - t);
    }
    return s;
}

// ---------------------------------------------------------------------------
// Kernel 1: HARDENED wave-register circuit.
// 512 blocks x 256 threads. Wave 0 of block b -> column b of W_in; block 0
// wave 1 -> bias column. R11 hardening vs R10 (which raced on replay):
//  - no early returns: inactive waves compute on zeros and join all barriers
//  - the per-layer LDS permute is bracketed by block-wide __syncthreads()
//    (WAR + RAW made explicit; no reliance on implicit intra-wave DS order)
// ---------------------------------------------------------------------------
__global__ __launch_bounds__(256)
void circuit_wave_kernel(const float* __restrict__ Wi, const float* __restrict__ b_in,
                         const float* __restrict__ qw,
                         ushort_t* __restrict__ Csm_r, ushort_t* __restrict__ Csm_i,
                         float* __restrict__ dr, float* __restrict__ di)
{
    __shared__ float gm[NL * NQ][8];
    __shared__ float2 scr[2048];   // waves 0,1 get 1024 float2 each

    const int tid = threadIdx.x;
    const int lane = tid & 63;
    const int wv = tid >> 6;
    const int blk = blockIdx.x;

    if (tid < NL * NQ) {
        float phi = qw[tid * 3 + 0], theta = qw[tid * 3 + 1], omega = qw[tid * 3 + 2];
        float ch = cosf(theta * 0.5f), sh = sinf(theta * 0.5f);
        float a = 0.5f * (phi + omega), b = 0.5f * (phi - omega);
        float ca = cosf(a), sa = sinf(a);
        float cb = cosf(b), sb = sinf(b);
        gm[tid][0] =  ch * ca;  gm[tid][1] = -ch * sa;   // m00
        gm[tid][2] = -sh * cb;  gm[tid][3] = -sh * sb;   // m01
        gm[tid][4] =  sh * cb;  gm[tid][5] = -sh * sb;   // m10
        gm[tid][6] =  ch * ca;  gm[tid][7] =  ch * sa;   // m11
    }
    __syncthreads();

    const int jcol = (wv == 0) ? blk : ((blk == 0 && wv == 1) ? SEQ : -1);
    const bool active = (jcol >= 0);

    float2 P[16];
#pragma unroll
    for (int r = 0; r < 16; ++r) P[r] = make_float2(0.f, 0.f);
    if (active) {
        if (jcol < SEQ) {
#pragma unroll
            for (int r = 0; r < 16; ++r)
                P[r].x = Wi[(size_t)(lane * 16 + r) * SEQ + jcol];
        } else {
#pragma unroll
            for (int r = 0; r < 16; ++r)
                P[r].x = b_in[lane * 16 + r] + 1e-6f;
        }
    }
    float2* wscr = scr + (wv & 1) * 1024;   // wv in {0,1} whenever active

#pragma unroll
    for (int l = 0; l < NL; ++l) {
        // --- 10 single-qubit gates (executed by all waves; zeros are inert) ---
#pragma unroll
        for (int w = 0; w < NQ; ++w) {
            const float* m = gm[l * NQ + w];
            float m00r = m[0], m00i = m[1], m01r = m[2], m01i = m[3];
            float m10r = m[4], m10i = m[5], m11r = m[6], m11i = m[7];
            if (w <= 5) {
                const int lb = 5 - w;
                const int mask = 1 << lb;
                const int myb = (lane >> lb) & 1;
                float cAr = myb ? m11r : m00r, cAi = myb ? m11i : m00i;
                float cQr = myb ? m10r : m01r, cQi = myb ? m10i : m01i;
#pragma unroll
                for (int r = 0; r < 16; ++r) {
                    float ar = P[r].x, ai = P[r].y;
                    float qr_ = __shfl_xor(ar, mask, 64);
                    float qi_ = __shfl_xor(ai, mask, 64);
                    P[r].x = cAr * ar - cAi * ai + cQr * qr_ - cQi * qi_;
                    P[r].y = cAr * ai + cAi * ar + cQr * qi_ + cQi * qr_;
                }
            } else {
                const int mk = 1 << (9 - w);
#pragma unroll
                for (int r0 = 0; r0 < 16; ++r0) {
                    if (r0 & mk) continue;
                    float2 a0 = P[r0], a1 = P[r0 | mk];
                    float2 n0, n1;
                    n0.x = m00r * a0.x - m00i * a0.y + m01r * a1.x - m01i * a1.y;
                    n0.y = m00r * a0.y + m00i * a0.x + m01r * a1.y + m01i * a1.x;
                    n1.x = m10r * a0.x - m10i * a0.y + m11r * a1.x - m11i * a1.y;
                    n1.y = m10r * a0.y + m10i * a0.x + m11r * a1.y + m11i * a1.x;
                    P[r0] = n0; P[r0 | mk] = n1;
                }
            }
        }
        // --- layer permutation via LDS, explicitly barrier-bracketed ---
        const int rr = l % (NQ - 1) + 1;
        __syncthreads();   // WAR: previous layer's reads complete before writes
        if (active) {
#pragma unroll
            for (int r = 0; r < 16; ++r) wscr[lane * 16 + r] = P[r];
        }
        __syncthreads();   // RAW: all writes visible before gathers
        if (active) {
            int pl = permf(lane << 4, rr);
#pragma unroll
            for (int r = 0; r < 16; ++r) {
                int src = pl ^ permf(r, rr);   // permf(r, rr) folds to a constant
                P[r] = wscr[src];
            }
        }
    }

    if (active) {
        if (jcol < SEQ) {
#pragma unroll
            for (int r = 0; r < 16; ++r) {
                int s = lane * 16 + r;
                Csm_r[(size_t)s * SEQ + jcol] = f2h(P[r].x);
                Csm_i[(size_t)s * SEQ + jcol] = f2h(P[r].y);
            }
        } else {
#pragma unroll
            for (int r = 0; r < 16; ++r) {
                dr[lane * 16 + r] = P[r].x;
                di[lane * 16 + r] = P[r].y;
            }
        }
    }
}

// ---------------------------------------------------------------------------
// Kernel 2: fused f16-MFMA GEMM + probs + signed partials.
// (Verbatim R3/R9, standalone-replay-proven: in-loop fp32->f16 pack.)
// ---------------------------------------------------------------------------
#define GBM 128
#define GBNC 64
#define GBK 32
#define LDA 40   // half stride for LDS tiles
#define LDP 65   // float stride for probs tile

__global__ __launch_bounds__(256)
void gemm_fused_kernel(const float* __restrict__ x,
                       const ushort_t* __restrict__ Crt_r, const ushort_t* __restrict__ Crt_i,
                       const float* __restrict__ dr, const float* __restrict__ di,
                       float* __restrict__ part)
{
    __shared__ __align__(16) char lds[GBM * LDP * 4];  // 33280 B (probs tile is max)
    ushort_t* Ash = (ushort_t*)lds;            // 128*40 halves = 10240 B
    ushort_t* Bsr = Ash + GBM * LDA;           // 64*40 = 5120 B
    ushort_t* Bsi = Bsr + GBNC * LDA;          // 64*40 = 5120 B
    float*    Ps  = (float*)lds;               // reused after K-loop
    __shared__ float drs[GBNC], dis[GBNC];

    const int tid = threadIdx.x;
    const int bm = blockIdx.x, bn = blockIdx.y;
    const int lane = tid & 63, wv = tid >> 6;
    const int n0 = bn * GBNC;

    if (tid < GBNC) { drs[tid] = dr[n0 + tid]; dis[tid] = di[n0 + tid]; }

    float4v accr[2][4], acci[2][4];
#pragma unroll
    for (int a = 0; a < 2; ++a)
#pragma unroll
        for (int b = 0; b < 4; ++b) { accr[a][b] = (float4v)0.f; acci[a][b] = (float4v)0.f; }

    const int sr = tid >> 1, ko = (tid & 1) * 16;
    const float* xa = x + (size_t)(bm * GBM + sr) * SEQ + ko;
    const int bsel = tid >> 7;
    const int nr = (tid & 127) >> 1;
    const int bko = (tid & 1) * 16;
    const ushort_t* bsrc = (bsel ? Crt_i : Crt_r) + (size_t)(n0 + nr) * SEQ + bko;
    ushort_t* bdst = (bsel ? Bsi : Bsr) + nr * LDA + bko;

    const int fm = lane & 15, kq = (lane >> 4) * 8;
    const int wrow = wv * 32;

    for (int k0 = 0; k0 < SEQ; k0 += GBK) {
        float fv[16];
        *(float4*)&fv[0]  = *(const float4*)(xa + k0);
        *(float4*)&fv[4]  = *(const float4*)(xa + k0 + 4);
        *(float4*)&fv[8]  = *(const float4*)(xa + k0 + 8);
        *(float4*)&fv[12] = *(const float4*)(xa + k0 + 12);
        uint_t pk[8];
#pragma unroll
        for (int i = 0; i < 8; ++i) pk[i] = pkh(fv[2 * i], fv[2 * i + 1]);
        *(uint4*)(Ash + sr * LDA + ko)     = make_uint4(pk[0], pk[1], pk[2], pk[3]);
        *(uint4*)(Ash + sr * LDA + ko + 8) = make_uint4(pk[4], pk[5], pk[6], pk[7]);
        uint4 b0 = *(const uint4*)(bsrc + k0);
        uint4 b1 = *(const uint4*)(bsrc + k0 + 8);
        *(uint4*)bdst       = b0;
        *(uint4*)(bdst + 8) = b1;
        __syncthreads();

        half8 ah0 = *(half8*)(Ash + (wrow + fm) * LDA + kq);
        half8 ah1 = *(half8*)(Ash + (wrow + 16 + fm) * LDA + kq);
#pragma unroll
        for (int nt = 0; nt < 4; ++nt) {
            half8 br = *(half8*)(Bsr + (nt * 16 + fm) * LDA + kq);
            half8 bi = *(half8*)(Bsi + (nt * 16 + fm) * LDA + kq);
            accr[0][nt] = __builtin_amdgcn_mfma_f32_16x16x32_f16(ah0, br, accr[0][nt], 0, 0, 0);
            accr[1][nt] = __builtin_amdgcn_mfma_f32_16x16x32_f16(ah1, br, accr[1][nt], 0, 0, 0);
            acci[0][nt] = __builtin_amdgcn_mfma_f32_16x16x32_f16(ah0, bi, acci[0][nt], 0, 0, 0);
            acci[1][nt] = __builtin_amdgcn_mfma_f32_16x16x32_f16(ah1, bi, acci[1][nt], 0, 0, 0);
        }
        __syncthreads();
    }

    const int rq = (lane >> 4) * 4;
#pragma unroll
    for (int mt = 0; mt < 2; ++mt)
#pragma unroll
        for (int nt = 0; nt < 4; ++nt) {
            float drv = drs[nt * 16 + fm], div = dis[nt * 16 + fm];
#pragma unroll
            for (int reg = 0; reg < 4; ++reg) {
                int lrow = wrow + mt * 16 + rq + reg;
                float zr = accr[mt][nt][reg] + drv;
                float zi = acci[mt][nt][reg] + div;
                Ps[lrow * LDP + nt * 16 + fm] = zr * zr + zi * zi;
            }
        }
    __syncthreads();

    {
        const int row = tid >> 1, hh = tid & 1;
        const float* pr = Ps + row * LDP + hh * 32;
        float nrm = 0.f, e0 = 0.f, e1 = 0.f, e2 = 0.f, e3 = 0.f, e4 = 0.f, e5 = 0.f;
#pragma unroll
        for (int i = 0; i < 32; ++i) {
            float p = pr[i];
            int c = hh * 32 + i;
            nrm += p;
            e0 += ((c >> 5) & 1) ? -p : p;   // k=4
            e1 += ((c >> 4) & 1) ? -p : p;   // k=5
            e2 += ((c >> 3) & 1) ? -p : p;   // k=6
            e3 += ((c >> 2) & 1) ? -p : p;   // k=7
            e4 += ((c >> 1) & 1) ? -p : p;   // k=8
            e5 += (c & 1) ? -p : p;          // k=9
        }
        size_t base = ((size_t)(bm * GBM + row) * 32 + (bn * 2 + hh)) * 8;
        part[base + 0] = nrm;
        part[base + 1] = e0; part[base + 2] = e1; part[base + 3] = e2;
        part[base + 4] = e3; part[base + 5] = e4; part[base + 6] = e5;
    }
}

// ---------------------------------------------------------------------------
// Kernel 3: per-row wave-parallel combine of 32 partials + W_out epilogue.
// (Verbatim R3/R8/R9, standalone-replay-proven.)
// ---------------------------------------------------------------------------
__global__ __launch_bounds__(128)
void finalize_kernel(const float* __restrict__ part, const float* __restrict__ W_out,
                     const float* __restrict__ b_out, float* __restrict__ out)
{
    __shared__ float evf[16];
    const int row = blockIdx.x, tid = threadIdx.x;

    if (tid < 64) {
        float v[11];
        if (tid < 32) {
            const float* p = part + ((size_t)row * 32 + tid) * 8;
            float4 a = *(const float4*)p;
            float4 b = *(const float4*)(p + 4);
            float nrm = a.x;
            int bnn = tid >> 1;   // s bits 9..6 = bits 3..0 of bnn
            v[0] = nrm;
            v[1] = (bnn & 8) ? -nrm : nrm;
            v[2] = (bnn & 4) ? -nrm : nrm;
            v[3] = (bnn & 2) ? -nrm : nrm;
            v[4] = (bnn & 1) ? -nrm : nrm;
            v[5] = a.y; v[6] = a.z; v[7] = a.w;
            v[8] = b.x; v[9] = b.y; v[10] = b.z;
        } else {
#pragma unroll
            for (int k = 0; k < 11; ++k) v[k] = 0.f;
        }
#pragma unroll
        for (int m = 16; m; m >>= 1)
#pragma unroll
            for (int k = 0; k < 11; ++k) v[k] += __shfl_xor(v[k], m, 64);
        if (tid == 0) {
            float inv = 1.0f / v[0];
#pragma unroll
            for (int k = 0; k < 10; ++k) evf[k] = v[k + 1] * inv;
        }
    }
    __syncthreads();
    if (tid < PRED) {
        float o = b_out[tid];
#pragma unroll
        for (int k = 0; k < NQ; ++k) o = fmaf(W_out[tid * NQ + k], evf[k], o);
        out[(size_t)row * PRED + tid] = o;
    }
}

extern "C" void kernel_launch(void* const* d_in, const int* in_sizes, int n_in,
                              void* d_out, int out_size, void* d_ws, size_t ws_size,
                              hipStream_t stream) {
    const float* x     = (const float*)d_in[0];
    const float* W_in  = (const float*)d_in[1];
    const float* b_in  = (const float*)d_in[2];
    const float* qw    = (const float*)d_in[3];
    const float* W_out = (const float*)d_in[4];
    const float* b_out = (const float*)d_in[5];
    float* out = (float*)d_out;

    char* w = (char*)d_ws;
    const size_t MB = 1u << 20;
    ushort_t* Csm_r = (ushort_t*)w;               // 1 MB  [s][j]
    ushort_t* Csm_i = (ushort_t*)(w + 1 * MB);    // 1 MB
    float*    dr    = (float*)(w + 2 * MB);       // 4 KB
    float*    di    = dr + DIM;                   // 4 KB
    float*    part  = (float*)(w + 3 * MB);       // 4 MB

    circuit_wave_kernel<<<512, 256, 0, stream>>>(W_in, b_in, qw, Csm_r, Csm_i, dr, di);
    dim3 g2(NROWS / GBM, DIM / GBNC);
    gemm_fused_kernel<<<g2, 256, 0, stream>>>(x, Csm_r, Csm_i, dr, di, part);
    finalize_kernel<<<NROWS, 128, 0, stream>>>(part, W_out, b_out, out);
}

// Round 12
// 126.688 us; speedup vs baseline: 3.3209x; 1.0316x over previous
//
#include <hip/hip_runtime.h>
#include <math.h>

#define DIM 1024
#define NQ 10
#define NL 4
#define SEQ 512
#define NROWS 4096
#define PRED 96

typedef unsigned short ushort_t;
typedef unsigned int uint_t;
using half8   = __attribute__((ext_vector_type(8))) _Float16;
using float4v = __attribute__((ext_vector_type(4))) float;

__device__ inline ushort_t f2h(float f) { _Float16 h = (_Float16)f; return *(ushort_t*)&h; }
__device__ inline uint_t pkh(float a, float b) {
    _Float16 ha = (_Float16)a, hb = (_Float16)b;   // RTE v_cvt_f16_f32
    return (uint_t)(*(ushort_t*)&ha) | ((uint_t)(*(ushort_t*)&hb) << 16);
}

// XOR-ladder layer permutation (GF(2)-linear). Verified R1-R5, R11.
__device__ inline int permf(int s, int r) {
#pragma unroll
    for (int c = 9; c >= 0; --c) {
        int t = (c + r) % 10;
        s ^= ((s >> (9 - c)) & 1) << (9 - t);
    }
    return s;
}

// ---------------------------------------------------------------------------
// Kernel 1: wave-register circuit, 64-thread blocks (R12 re-shape of the
// R11-proven kernel: same math, same barrier-bracketed LDS permute, same
// I/O pattern — but every wave does real work; no zero-padding waves).
// Block b (0..511) -> column b of W_in; block 512 -> bias column.
// ---------------------------------------------------------------------------
__global__ __launch_bounds__(64)
void circuit_wave64_kernel(const float* __restrict__ Wi, const float* __restrict__ b_in,
                           const float* __restrict__ qw,
                           ushort_t* __restrict__ Csm_r, ushort_t* __restrict__ Csm_i,
                           float* __restrict__ dr, float* __restrict__ di)
{
    __shared__ float gm[NL * NQ][8];
    __shared__ float2 wscr[1024];

    const int lane = threadIdx.x;          // 0..63 (block == one wave)
    const int jcol = blockIdx.x;           // 0..512

    if (lane < NL * NQ) {
        float phi = qw[lane * 3 + 0], theta = qw[lane * 3 + 1], omega = qw[lane * 3 + 2];
        float ch = cosf(theta * 0.5f), sh = sinf(theta * 0.5f);
        float a = 0.5f * (phi + omega), b = 0.5f * (phi - omega);
        float ca = cosf(a), sa = sinf(a);
        float cb = cosf(b), sb = sinf(b);
        gm[lane][0] =  ch * ca;  gm[lane][1] = -ch * sa;   // m00
        gm[lane][2] = -sh * cb;  gm[lane][3] = -sh * sb;   // m01
        gm[lane][4] =  sh * cb;  gm[lane][5] = -sh * sb;   // m10
        gm[lane][6] =  ch * ca;  gm[lane][7] =  ch * sa;   // m11
    }
    __syncthreads();

    float2 P[16];
    if (jcol < SEQ) {
#pragma unroll
        for (int r = 0; r < 16; ++r)
            P[r] = make_float2(Wi[(size_t)(lane * 16 + r) * SEQ + jcol], 0.f);
    } else {
#pragma unroll
        for (int r = 0; r < 16; ++r)
            P[r] = make_float2(b_in[lane * 16 + r] + 1e-6f, 0.f);
    }

#pragma unroll
    for (int l = 0; l < NL; ++l) {
        // --- 10 single-qubit gates (R11-proven math) ---
#pragma unroll
        for (int w = 0; w < NQ; ++w) {
            const float* m = gm[l * NQ + w];
            float m00r = m[0], m00i = m[1], m01r = m[2], m01i = m[3];
            float m10r = m[4], m10i = m[5], m11r = m[6], m11i = m[7];
            if (w <= 5) {
                const int lb = 5 - w;
                const int mask = 1 << lb;
                const int myb = (lane >> lb) & 1;
                float cAr = myb ? m11r : m00r, cAi = myb ? m11i : m00i;
                float cQr = myb ? m10r : m01r, cQi = myb ? m10i : m01i;
#pragma unroll
                for (int r = 0; r < 16; ++r) {
                    float ar = P[r].x, ai = P[r].y;
                    float qr_ = __shfl_xor(ar, mask, 64);
                    float qi_ = __shfl_xor(ai, mask, 64);
                    P[r].x = cAr * ar - cAi * ai + cQr * qr_ - cQi * qi_;
                    P[r].y = cAr * ai + cAi * ar + cQr * qi_ + cQi * qr_;
                }
            } else {
                const int mk = 1 << (9 - w);
#pragma unroll
                for (int r0 = 0; r0 < 16; ++r0) {
                    if (r0 & mk) continue;
                    float2 a0 = P[r0], a1 = P[r0 | mk];
                    float2 n0, n1;
                    n0.x = m00r * a0.x - m00i * a0.y + m01r * a1.x - m01i * a1.y;
                    n0.y = m00r * a0.y + m00i * a0.x + m01r * a1.y + m01i * a1.x;
                    n1.x = m10r * a0.x - m10i * a0.y + m11r * a1.x - m11i * a1.y;
                    n1.y = m10r * a0.y + m10i * a0.x + m11r * a1.y + m11i * a1.x;
                    P[r0] = n0; P[r0 | mk] = n1;
                }
            }
        }
        // --- layer permutation via LDS, barrier-bracketed (R11-proven safe) ---
        const int rr = l % (NQ - 1) + 1;
        __syncthreads();   // WAR
#pragma unroll
        for (int r = 0; r < 16; ++r) wscr[lane * 16 + r] = P[r];
        __syncthreads();   // RAW
        int pl = permf(lane << 4, rr);
#pragma unroll
        for (int r = 0; r < 16; ++r) {
            int src = pl ^ permf(r, rr);   // permf(r, rr) folds to a constant
            P[r] = wscr[src];
        }
    }

    if (jcol < SEQ) {
#pragma unroll
        for (int r = 0; r < 16; ++r) {
            int s = lane * 16 + r;
            Csm_r[(size_t)s * SEQ + jcol] = f2h(P[r].x);
            Csm_i[(size_t)s * SEQ + jcol] = f2h(P[r].y);
        }
    } else {
#pragma unroll
        for (int r = 0; r < 16; ++r) {
            dr[lane * 16 + r] = P[r].x;
            di[lane * 16 + r] = P[r].y;
        }
    }
}

// ---------------------------------------------------------------------------
// Kernel 2: fused f16-MFMA GEMM + probs + signed partials.
// (Verbatim R3/R9/R11, standalone-replay-proven.)
// ---------------------------------------------------------------------------
#define GBM 128
#define GBNC 64
#define GBK 32
#define LDA 40   // half stride for LDS tiles
#define LDP 65   // float stride for probs tile

__global__ __launch_bounds__(256)
void gemm_fused_kernel(const float* __restrict__ x,
                       const ushort_t* __restrict__ Crt_r, const ushort_t* __restrict__ Crt_i,
                       const float* __restrict__ dr, const float* __restrict__ di,
                       float* __restrict__ part)
{
    __shared__ __align__(16) char lds[GBM * LDP * 4];  // 33280 B (probs tile is max)
    ushort_t* Ash = (ushort_t*)lds;            // 128*40 halves = 10240 B
    ushort_t* Bsr = Ash + GBM * LDA;           // 64*40 = 5120 B
    ushort_t* Bsi = Bsr + GBNC * LDA;          // 64*40 = 5120 B
    float*    Ps  = (float*)lds;               // reused after K-loop
    __shared__ float drs[GBNC], dis[GBNC];

    const int tid = threadIdx.x;
    const int bm = blockIdx.x, bn = blockIdx.y;
    const int lane = tid & 63, wv = tid >> 6;
    const int n0 = bn * GBNC;

    if (tid < GBNC) { drs[tid] = dr[n0 + tid]; dis[tid] = di[n0 + tid]; }

    float4v accr[2][4], acci[2][4];
#pragma unroll
    for (int a = 0; a < 2; ++a)
#pragma unroll
        for (int b = 0; b < 4; ++b) { accr[a][b] = (float4v)0.f; acci[a][b] = (float4v)0.f; }

    const int sr = tid >> 1, ko = (tid & 1) * 16;
    const float* xa = x + (size_t)(bm * GBM + sr) * SEQ + ko;
    const int bsel = tid >> 7;
    const int nr = (tid & 127) >> 1;
    const int bko = (tid & 1) * 16;
    const ushort_t* bsrc = (bsel ? Crt_i : Crt_r) + (size_t)(n0 + nr) * SEQ + bko;
    ushort_t* bdst = (bsel ? Bsi : Bsr) + nr * LDA + bko;

    const int fm = lane & 15, kq = (lane >> 4) * 8;
    const int wrow = wv * 32;

    for (int k0 = 0; k0 < SEQ; k0 += GBK) {
        float fv[16];
        *(float4*)&fv[0]  = *(const float4*)(xa + k0);
        *(float4*)&fv[4]  = *(const float4*)(xa + k0 + 4);
        *(float4*)&fv[8]  = *(const float4*)(xa + k0 + 8);
        *(float4*)&fv[12] = *(const float4*)(xa + k0 + 12);
        uint_t pk[8];
#pragma unroll
        for (int i = 0; i < 8; ++i) pk[i] = pkh(fv[2 * i], fv[2 * i + 1]);
        *(uint4*)(Ash + sr * LDA + ko)     = make_uint4(pk[0], pk[1], pk[2], pk[3]);
        *(uint4*)(Ash + sr * LDA + ko + 8) = make_uint4(pk[4], pk[5], pk[6], pk[7]);
        uint4 b0 = *(const uint4*)(bsrc + k0);
        uint4 b1 = *(const uint4*)(bsrc + k0 + 8);
        *(uint4*)bdst       = b0;
        *(uint4*)(bdst + 8) = b1;
        __syncthreads();

        half8 ah0 = *(half8*)(Ash + (wrow + fm) * LDA + kq);
        half8 ah1 = *(half8*)(Ash + (wrow + 16 + fm) * LDA + kq);
#pragma unroll
        for (int nt = 0; nt < 4; ++nt) {
            half8 br = *(half8*)(Bsr + (nt * 16 + fm) * LDA + kq);
            half8 bi = *(half8*)(Bsi + (nt * 16 + fm) * LDA + kq);
            accr[0][nt] = __builtin_amdgcn_mfma_f32_16x16x32_f16(ah0, br, accr[0][nt], 0, 0, 0);
            accr[1][nt] = __builtin_amdgcn_mfma_f32_16x16x32_f16(ah1, br, accr[1][nt], 0, 0, 0);
            acci[0][nt] = __builtin_amdgcn_mfma_f32_16x16x32_f16(ah0, bi, acci[0][nt], 0, 0, 0);
            acci[1][nt] = __builtin_amdgcn_mfma_f32_16x16x32_f16(ah1, bi, acci[1][nt], 0, 0, 0);
        }
        __syncthreads();
    }

    const int rq = (lane >> 4) * 4;
#pragma unroll
    for (int mt = 0; mt < 2; ++mt)
#pragma unroll
        for (int nt = 0; nt < 4; ++nt) {
            float drv = drs[nt * 16 + fm], div = dis[nt * 16 + fm];
#pragma unroll
            for (int reg = 0; reg < 4; ++reg) {
                int lrow = wrow + mt * 16 + rq + reg;
                float zr = accr[mt][nt][reg] + drv;
                float zi = acci[mt][nt][reg] + div;
                Ps[lrow * LDP + nt * 16 + fm] = zr * zr + zi * zi;
            }
        }
    __syncthreads();

    {
        const int row = tid >> 1, hh = tid & 1;
        const float* pr = Ps + row * LDP + hh * 32;
        float nrm = 0.f, e0 = 0.f, e1 = 0.f, e2 = 0.f, e3 = 0.f, e4 = 0.f, e5 = 0.f;
#pragma unroll
        for (int i = 0; i < 32; ++i) {
            float p = pr[i];
            int c = hh * 32 + i;
            nrm += p;
            e0 += ((c >> 5) & 1) ? -p : p;   // k=4
            e1 += ((c >> 4) & 1) ? -p : p;   // k=5
            e2 += ((c >> 3) & 1) ? -p : p;   // k=6
            e3 += ((c >> 2) & 1) ? -p : p;   // k=7
            e4 += ((c >> 1) & 1) ? -p : p;   // k=8
            e5 += (c & 1) ? -p : p;          // k=9
        }
        size_t base = ((size_t)(bm * GBM + row) * 32 + (bn * 2 + hh)) * 8;
        part[base + 0] = nrm;
        part[base + 1] = e0; part[base + 2] = e1; part[base + 3] = e2;
        part[base + 4] = e3; part[base + 5] = e4; part[base + 6] = e5;
    }
}

// ---------------------------------------------------------------------------
// Kernel 3: per-row wave-parallel combine of 32 partials + W_out epilogue.
// (Verbatim R3/R8/R9/R11, standalone-replay-proven.)
// ---------------------------------------------------------------------------
__global__ __launch_bounds__(128)
void finalize_kernel(const float* __restrict__ part, const float* __restrict__ W_out,
                     const float* __restrict__ b_out, float* __restrict__ out)
{
    __shared__ float evf[16];
    const int row = blockIdx.x, tid = threadIdx.x;

    if (tid < 64) {
        float v[11];
        if (tid < 32) {
            const float* p = part + ((size_t)row * 32 + tid) * 8;
            float4 a = *(const float4*)p;
            float4 b = *(const float4*)(p + 4);
            float nrm = a.x;
            int bnn = tid >> 1;   // s bits 9..6 = bits 3..0 of bnn
            v[0] = nrm;
            v[1] = (bnn & 8) ? -nrm : nrm;
            v[2] = (bnn & 4) ? -nrm : nrm;
            v[3] = (bnn & 2) ? -nrm : nrm;
            v[4] = (bnn & 1) ? -nrm : nrm;
            v[5] = a.y; v[6] = a.z; v[7] = a.w;
            v[8] = b.x; v[9] = b.y; v[10] = b.z;
        } else {
#pragma unroll
            for (int k = 0; k < 11; ++k) v[k] = 0.f;
        }
#pragma unroll
        for (int m = 16; m; m >>= 1)
#pragma unroll
            for (int k = 0; k < 11; ++k) v[k] += __shfl_xor(v[k], m, 64);
        if (tid == 0) {
            float inv = 1.0f / v[0];
#pragma unroll
            for (int k = 0; k < 10; ++k) evf[k] = v[k + 1] * inv;
        }
    }
    __syncthreads();
    if (tid < PRED) {
        float o = b_out[tid];
#pragma unroll
        for (int k = 0; k < NQ; ++k) o = fmaf(W_out[tid * NQ + k], evf[k], o);
        out[(size_t)row * PRED + tid] = o;
    }
}

extern "C" void kernel_launch(void* const* d_in, const int* in_sizes, int n_in,
                              void* d_out, int out_size, void* d_ws, size_t ws_size,
                              hipStream_t stream) {
    const float* x     = (const float*)d_in[0];
    const float* W_in  = (const float*)d_in[1];
    const float* b_in  = (const float*)d_in[2];
    const float* qw    = (const float*)d_in[3];
    const float* W_out = (const float*)d_in[4];
    const float* b_out = (const float*)d_in[5];
    float* out = (float*)d_out;

    char* w = (char*)d_ws;
    const size_t MB = 1u << 20;
    ushort_t* Csm_r = (ushort_t*)w;               // 1 MB  [s][j]
    ushort_t* Csm_i = (ushort_t*)(w + 1 * MB);    // 1 MB
    float*    dr    = (float*)(w + 2 * MB);       // 4 KB
    float*    di    = dr + DIM;                   // 4 KB
    float*    part  = (float*)(w + 3 * MB);       // 4 MB

    circuit_wave64_kernel<<<SEQ + 1, 64, 0, stream>>>(W_in, b_in, qw, Csm_r, Csm_i, dr, di);
    dim3 g2(NROWS / GBM, DIM / GBNC);
    gemm_fused_kernel<<<g2, 256, 0, stream>>>(x, Csm_r, Csm_i, dr, di, part);
    finalize_kernel<<<NROWS, 128, 0, stream>>>(part, W_out, b_out, out);
}

// Round 13
// 124.553 us; speedup vs baseline: 3.3778x; 1.0171x over previous
//
#include <hip/hip_runtime.h>
#include <math.h>

#define DIM 1024
#define NQ 10
#define NL 4
#define SEQ 512
#define NROWS 4096
#define PRED 96

typedef unsigned short ushort_t;
typedef unsigned int uint_t;
using half8   = __attribute__((ext_vector_type(8))) _Float16;
using float4v = __attribute__((ext_vector_type(4))) float;

__device__ inline ushort_t f2h(float f) { _Float16 h = (_Float16)f; return *(ushort_t*)&h; }
__device__ inline uint_t pkh(float a, float b) {
    _Float16 ha = (_Float16)a, hb = (_Float16)b;   // RTE v_cvt_f16_f32
    return (uint_t)(*(ushort_t*)&ha) | ((uint_t)(*(ushort_t*)&hb) << 16);
}

// XOR-ladder layer permutation (GF(2)-linear). Verified R1-R5, R11, R12.
__device__ inline int permf(int s, int r) {
#pragma unroll
    for (int c = 9; c >= 0; --c) {
        int t = (c + r) % 10;
        s ^= ((s >> (9 - c)) & 1) << (9 - t);
    }
    return s;
}

// ---------------------------------------------------------------------------
// Kernel 0: W_in (1024x512) -> W_inT (512x1024), fp32 LDS tile transpose.
// 64x64 tiles, 256 threads, coalesced float4 in and out.
// ---------------------------------------------------------------------------
__global__ __launch_bounds__(256)
void transpose_win_kernel(const float* __restrict__ Wi, float* __restrict__ WiT)
{
    __shared__ float Ts[64][68];   // [k][j], pad to break bank conflicts
    const int tid = threadIdx.x;
    const int k0 = blockIdx.x * 64;   // 16 tiles over DIM
    const int j0 = blockIdx.y * 64;   // 8 tiles over SEQ

    const int jj = (tid & 15) * 4;
    const int kk = tid >> 4;
#pragma unroll
    for (int i = 0; i < 4; ++i) {
        int k = kk + i * 16;
        float4 v = *(const float4*)(Wi + (size_t)(k0 + k) * SEQ + j0 + jj);
        Ts[k][jj] = v.x; Ts[k][jj + 1] = v.y; Ts[k][jj + 2] = v.z; Ts[k][jj + 3] = v.w;
    }
    __syncthreads();
    const int kk2 = (tid & 15) * 4;
    const int jj2 = tid >> 4;
#pragma unroll
    for (int i = 0; i < 4; ++i) {
        int j = jj2 + i * 16;
        float4 v = make_float4(Ts[kk2][j], Ts[kk2 + 1][j], Ts[kk2 + 2][j], Ts[kk2 + 3][j]);
        *(float4*)(WiT + (size_t)(j0 + j) * DIM + k0 + kk2) = v;
    }
}

// ---------------------------------------------------------------------------
// Kernel 1: wave-register circuit, 64-thread blocks (R12-proven math and
// barrier-bracketed LDS permute). R13 deltas: coalesced loads from W_inT
// rows; coalesced [j][s] packed-uint4 f16 stores (R4-proven output path).
// Block b (0..511) -> column b; block 512 -> bias column (dr/di fp32).
// ---------------------------------------------------------------------------
__global__ __launch_bounds__(64)
void circuit_wave64_kernel(const float* __restrict__ WiT, const float* __restrict__ b_in,
                           const float* __restrict__ qw,
                           ushort_t* __restrict__ Cjm_r, ushort_t* __restrict__ Cjm_i,
                           float* __restrict__ dr, float* __restrict__ di)
{
    __shared__ float gm[NL * NQ][8];
    __shared__ float2 wscr[1024];

    const int lane = threadIdx.x;          // block == one wave
    const int jcol = blockIdx.x;           // 0..512

    if (lane < NL * NQ) {
        float phi = qw[lane * 3 + 0], theta = qw[lane * 3 + 1], omega = qw[lane * 3 + 2];
        float ch = cosf(theta * 0.5f), sh = sinf(theta * 0.5f);
        float a = 0.5f * (phi + omega), b = 0.5f * (phi - omega);
        float ca = cosf(a), sa = sinf(a);
        float cb = cosf(b), sb = sinf(b);
        gm[lane][0] =  ch * ca;  gm[lane][1] = -ch * sa;   // m00
        gm[lane][2] = -sh * cb;  gm[lane][3] = -sh * sb;   // m01
        gm[lane][4] =  sh * cb;  gm[lane][5] = -sh * sb;   // m10
        gm[lane][6] =  ch * ca;  gm[lane][7] =  ch * sa;   // m11
    }
    __syncthreads();

    float2 P[16];
    if (jcol < SEQ) {
        const float* src = WiT + (size_t)jcol * DIM + lane * 16;
        float4 v0 = *(const float4*)(src);
        float4 v1 = *(const float4*)(src + 4);
        float4 v2 = *(const float4*)(src + 8);
        float4 v3 = *(const float4*)(src + 12);
        P[0]  = make_float2(v0.x, 0.f); P[1]  = make_float2(v0.y, 0.f);
        P[2]  = make_float2(v0.z, 0.f); P[3]  = make_float2(v0.w, 0.f);
        P[4]  = make_float2(v1.x, 0.f); P[5]  = make_float2(v1.y, 0.f);
        P[6]  = make_float2(v1.z, 0.f); P[7]  = make_float2(v1.w, 0.f);
        P[8]  = make_float2(v2.x, 0.f); P[9]  = make_float2(v2.y, 0.f);
        P[10] = make_float2(v2.z, 0.f); P[11] = make_float2(v2.w, 0.f);
        P[12] = make_float2(v3.x, 0.f); P[13] = make_float2(v3.y, 0.f);
        P[14] = make_float2(v3.z, 0.f); P[15] = make_float2(v3.w, 0.f);
    } else {
#pragma unroll
        for (int r = 0; r < 16; ++r)
            P[r] = make_float2(b_in[lane * 16 + r] + 1e-6f, 0.f);
    }

#pragma unroll
    for (int l = 0; l < NL; ++l) {
        // --- 10 single-qubit gates (R11/R12-proven math) ---
#pragma unroll
        for (int w = 0; w < NQ; ++w) {
            const float* m = gm[l * NQ + w];
            float m00r = m[0], m00i = m[1], m01r = m[2], m01i = m[3];
            float m10r = m[4], m10i = m[5], m11r = m[6], m11i = m[7];
            if (w <= 5) {
                const int lb = 5 - w;
                const int mask = 1 << lb;
                const int myb = (lane >> lb) & 1;
                float cAr = myb ? m11r : m00r, cAi = myb ? m11i : m00i;
                float cQr = myb ? m10r : m01r, cQi = myb ? m10i : m01i;
#pragma unroll
                for (int r = 0; r < 16; ++r) {
                    float ar = P[r].x, ai = P[r].y;
                    float qr_ = __shfl_xor(ar, mask, 64);
                    float qi_ = __shfl_xor(ai, mask, 64);
                    P[r].x = cAr * ar - cAi * ai + cQr * qr_ - cQi * qi_;
                    P[r].y = cAr * ai + cAi * ar + cQr * qi_ + cQi * qr_;
                }
            } else {
                const int mk = 1 << (9 - w);
#pragma unroll
                for (int r0 = 0; r0 < 16; ++r0) {
                    if (r0 & mk) continue;
                    float2 a0 = P[r0], a1 = P[r0 | mk];
                    float2 n0, n1;
                    n0.x = m00r * a0.x - m00i * a0.y + m01r * a1.x - m01i * a1.y;
                    n0.y = m00r * a0.y + m00i * a0.x + m01r * a1.y + m01i * a1.x;
                    n1.x = m10r * a0.x - m10i * a0.y + m11r * a1.x - m11i * a1.y;
                    n1.y = m10r * a0.y + m10i * a0.x + m11r * a1.y + m11i * a1.x;
                    P[r0] = n0; P[r0 | mk] = n1;
                }
            }
        }
        // --- layer permutation via LDS, barrier-bracketed (R11/R12-proven) ---
        const int rr = l % (NQ - 1) + 1;
        __syncthreads();   // WAR
#pragma unroll
        for (int r = 0; r < 16; ++r) wscr[lane * 16 + r] = P[r];
        __syncthreads();   // RAW
        int pl = permf(lane << 4, rr);
#pragma unroll
        for (int r = 0; r < 16; ++r) {
            int src = pl ^ permf(r, rr);   // permf(r, rr) folds to a constant
            P[r] = wscr[src];
        }
    }

    if (jcol < SEQ) {
        // R4-proven coalesced [j][s] packed store
        uint4 o0, o1, p0, p1;
        o0.x = pkh(P[0].x,  P[1].x);  o0.y = pkh(P[2].x,  P[3].x);
        o0.z = pkh(P[4].x,  P[5].x);  o0.w = pkh(P[6].x,  P[7].x);
        o1.x = pkh(P[8].x,  P[9].x);  o1.y = pkh(P[10].x, P[11].x);
        o1.z = pkh(P[12].x, P[13].x); o1.w = pkh(P[14].x, P[15].x);
        p0.x = pkh(P[0].y,  P[1].y);  p0.y = pkh(P[2].y,  P[3].y);
        p0.z = pkh(P[4].y,  P[5].y);  p0.w = pkh(P[6].y,  P[7].y);
        p1.x = pkh(P[8].y,  P[9].y);  p1.y = pkh(P[10].y, P[11].y);
        p1.z = pkh(P[12].y, P[13].y); p1.w = pkh(P[14].y, P[15].y);
        size_t base = (size_t)jcol * DIM + lane * 16;
        *(uint4*)(Cjm_r + base)     = o0;
        *(uint4*)(Cjm_r + base + 8) = o1;
        *(uint4*)(Cjm_i + base)     = p0;
        *(uint4*)(Cjm_i + base + 8) = p1;
    } else {
#pragma unroll
        for (int r = 0; r < 16; ++r) {
            dr[lane * 16 + r] = P[r].x;
            di[lane * 16 + r] = P[r].y;
        }
    }
}

// ---------------------------------------------------------------------------
// Kernel 2: transpose C from [j][s] to s-major [s][j]. (Verbatim R4, proven.)
// ---------------------------------------------------------------------------
__global__ __launch_bounds__(256)
void transpose_c_kernel(const ushort_t* __restrict__ in_r, const ushort_t* __restrict__ in_i,
                        ushort_t* __restrict__ out_r, ushort_t* __restrict__ out_i)
{
    __shared__ ushort_t Ts[64][80];   // [s][j], stride 160 B (16-aligned)
    const int tid = threadIdx.x;
    const int j0 = blockIdx.x * 64;
    const int s0 = blockIdx.y * 64;

    for (int a = 0; a < 2; ++a) {
        const ushort_t* in = a ? in_i : in_r;
        ushort_t* out = a ? out_i : out_r;
#pragma unroll
        for (int g = 0; g < 2; ++g) {
            int G = tid + g * 256;
            int jj = G >> 3, ch = G & 7;
            uint4 v = *(const uint4*)(in + (size_t)(j0 + jj) * DIM + s0 + ch * 8);
            const ushort_t* hv = (const ushort_t*)&v;
#pragma unroll
            for (int q = 0; q < 8; ++q) Ts[ch * 8 + q][jj] = hv[q];
        }
        __syncthreads();
#pragma unroll
        for (int g = 0; g < 2; ++g) {
            int G = tid + g * 256;
            int ss = G >> 3, jc = G & 7;
            uint4 v = *(const uint4*)(&Ts[ss][jc * 8]);
            *(uint4*)(out + (size_t)(s0 + ss) * SEQ + j0 + jc * 8) = v;
        }
        __syncthreads();
    }
}

// ---------------------------------------------------------------------------
// Kernel 3: fused f16-MFMA GEMM + probs + signed partials.
// (Verbatim R3/R9/R11/R12, standalone-replay-proven.)
// ---------------------------------------------------------------------------
#define GBM 128
#define GBNC 64
#define GBK 32
#define LDA 40   // half stride for LDS tiles
#define LDP 65   // float stride for probs tile

__global__ __launch_bounds__(256)
void gemm_fused_kernel(const float* __restrict__ x,
                       const ushort_t* __restrict__ Crt_r, const ushort_t* __restrict__ Crt_i,
                       const float* __restrict__ dr, const float* __restrict__ di,
                       float* __restrict__ part)
{
    __shared__ __align__(16) char lds[GBM * LDP * 4];  // 33280 B (probs tile is max)
    ushort_t* Ash = (ushort_t*)lds;            // 128*40 halves = 10240 B
    ushort_t* Bsr = Ash + GBM * LDA;           // 64*40 = 5120 B
    ushort_t* Bsi = Bsr + GBNC * LDA;          // 64*40 = 5120 B
    float*    Ps  = (float*)lds;               // reused after K-loop
    __shared__ float drs[GBNC], dis[GBNC];

    const int tid = threadIdx.x;
    const int bm = blockIdx.x, bn = blockIdx.y;
    const int lane = tid & 63, wv = tid >> 6;
    const int n0 = bn * GBNC;

    if (tid < GBNC) { drs[tid] = dr[n0 + tid]; dis[tid] = di[n0 + tid]; }

    float4v accr[2][4], acci[2][4];
#pragma unroll
    for (int a = 0; a < 2; ++a)
#pragma unroll
        for (int b = 0; b < 4; ++b) { accr[a][b] = (float4v)0.f; acci[a][b] = (float4v)0.f; }

    const int sr = tid >> 1, ko = (tid & 1) * 16;
    const float* xa = x + (size_t)(bm * GBM + sr) * SEQ + ko;
    const int bsel = tid >> 7;
    const int nr = (tid & 127) >> 1;
    const int bko = (tid & 1) * 16;
    const ushort_t* bsrc = (bsel ? Crt_i : Crt_r) + (size_t)(n0 + nr) * SEQ + bko;
    ushort_t* bdst = (bsel ? Bsi : Bsr) + nr * LDA + bko;

    const int fm = lane & 15, kq = (lane >> 4) * 8;
    const int wrow = wv * 32;

    for (int k0 = 0; k0 < SEQ; k0 += GBK) {
        float fv[16];
        *(float4*)&fv[0]  = *(const float4*)(xa + k0);
        *(float4*)&fv[4]  = *(const float4*)(xa + k0 + 4);
        *(float4*)&fv[8]  = *(const float4*)(xa + k0 + 8);
        *(float4*)&fv[12] = *(const float4*)(xa + k0 + 12);
        uint_t pk[8];
#pragma unroll
        for (int i = 0; i < 8; ++i) pk[i] = pkh(fv[2 * i], fv[2 * i + 1]);
        *(uint4*)(Ash + sr * LDA + ko)     = make_uint4(pk[0], pk[1], pk[2], pk[3]);
        *(uint4*)(Ash + sr * LDA + ko + 8) = make_uint4(pk[4], pk[5], pk[6], pk[7]);
        uint4 b0 = *(const uint4*)(bsrc + k0);
        uint4 b1 = *(const uint4*)(bsrc + k0 + 8);
        *(uint4*)bdst       = b0;
        *(uint4*)(bdst + 8) = b1;
        __syncthreads();

        half8 ah0 = *(half8*)(Ash + (wrow + fm) * LDA + kq);
        half8 ah1 = *(half8*)(Ash + (wrow + 16 + fm) * LDA + kq);
#pragma unroll
        for (int nt = 0; nt < 4; ++nt) {
            half8 br = *(half8*)(Bsr + (nt * 16 + fm) * LDA + kq);
            half8 bi = *(half8*)(Bsi + (nt * 16 + fm) * LDA + kq);
            accr[0][nt] = __builtin_amdgcn_mfma_f32_16x16x32_f16(ah0, br, accr[0][nt], 0, 0, 0);
            accr[1][nt] = __builtin_amdgcn_mfma_f32_16x16x32_f16(ah1, br, accr[1][nt], 0, 0, 0);
            acci[0][nt] = __builtin_amdgcn_mfma_f32_16x16x32_f16(ah0, bi, acci[0][nt], 0, 0, 0);
            acci[1][nt] = __builtin_amdgcn_mfma_f32_16x16x32_f16(ah1, bi, acci[1][nt], 0, 0, 0);
        }
        __syncthreads();
    }

    const int rq = (lane >> 4) * 4;
#pragma unroll
    for (int mt = 0; mt < 2; ++mt)
#pragma unroll
        for (int nt = 0; nt < 4; ++nt) {
            float drv = drs[nt * 16 + fm], div = dis[nt * 16 + fm];
#pragma unroll
            for (int reg = 0; reg < 4; ++reg) {
                int lrow = wrow + mt * 16 + rq + reg;
                float zr = accr[mt][nt][reg] + drv;
                float zi = acci[mt][nt][reg] + div;
                Ps[lrow * LDP + nt * 16 + fm] = zr * zr + zi * zi;
            }
        }
    __syncthreads();

    {
        const int row = tid >> 1, hh = tid & 1;
        const float* pr = Ps + row * LDP + hh * 32;
        float nrm = 0.f, e0 = 0.f, e1 = 0.f, e2 = 0.f, e3 = 0.f, e4 = 0.f, e5 = 0.f;
#pragma unroll
        for (int i = 0; i < 32; ++i) {
            float p = pr[i];
            int c = hh * 32 + i;
            nrm += p;
            e0 += ((c >> 5) & 1) ? -p : p;   // k=4
            e1 += ((c >> 4) & 1) ? -p : p;   // k=5
            e2 += ((c >> 3) & 1) ? -p : p;   // k=6
            e3 += ((c >> 2) & 1) ? -p : p;   // k=7
            e4 += ((c >> 1) & 1) ? -p : p;   // k=8
            e5 += (c & 1) ? -p : p;          // k=9
        }
        size_t base = ((size_t)(bm * GBM + row) * 32 + (bn * 2 + hh)) * 8;
        part[base + 0] = nrm;
        part[base + 1] = e0; part[base + 2] = e1; part[base + 3] = e2;
        part[base + 4] = e3; part[base + 5] = e4; part[base + 6] = e5;
    }
}

// ---------------------------------------------------------------------------
// Kernel 4: per-row wave-parallel combine of 32 partials + W_out epilogue.
// (Verbatim R3/R8/R9/R11/R12, standalone-replay-proven.)
// ---------------------------------------------------------------------------
__global__ __launch_bounds__(128)
void finalize_kernel(const float* __restrict__ part, const float* __restrict__ W_out,
                     const float* __restrict__ b_out, float* __restrict__ out)
{
    __shared__ float evf[16];
    const int row = blockIdx.x, tid = threadIdx.x;

    if (tid < 64) {
        float v[11];
        if (tid < 32) {
            const float* p = part + ((size_t)row * 32 + tid) * 8;
            float4 a = *(const float4*)p;
            float4 b = *(const float4*)(p + 4);
            float nrm = a.x;
            int bnn = tid >> 1;   // s bits 9..6 = bits 3..0 of bnn
            v[0] = nrm;
            v[1] = (bnn & 8) ? -nrm : nrm;
            v[2] = (bnn & 4) ? -nrm : nrm;
            v[3] = (bnn & 2) ? -nrm : nrm;
            v[4] = (bnn & 1) ? -nrm : nrm;
            v[5] = a.y; v[6] = a.z; v[7] = a.w;
            v[8] = b.x; v[9] = b.y; v[10] = b.z;
        } else {
#pragma unroll
            for (int k = 0; k < 11; ++k) v[k] = 0.f;
        }
#pragma unroll
        for (int m = 16; m; m >>= 1)
#pragma unroll
            for (int k = 0; k < 11; ++k) v[k] += __shfl_xor(v[k], m, 64);
        if (tid == 0) {
            float inv = 1.0f / v[0];
#pragma unroll
            for (int k = 0; k < 10; ++k) evf[k] = v[k + 1] * inv;
        }
    }
    __syncthreads();
    if (tid < PRED) {
        float o = b_out[tid];
#pragma unroll
        for (int k = 0; k < NQ; ++k) o = fmaf(W_out[tid * NQ + k], evf[k], o);
        out[(size_t)row * PRED + tid] = o;
    }
}

extern "C" void kernel_launch(void* const* d_in, const int* in_sizes, int n_in,
                              void* d_out, int out_size, void* d_ws, size_t ws_size,
                              hipStream_t stream) {
    const float* x     = (const float*)d_in[0];
    const float* W_in  = (const float*)d_in[1];
    const float* b_in  = (const float*)d_in[2];
    const float* qw    = (const float*)d_in[3];
    const float* W_out = (const float*)d_in[4];
    const float* b_out = (const float*)d_in[5];
    float* out = (float*)d_out;

    char* w = (char*)d_ws;
    const size_t MB = 1u << 20;
    float*    WiT   = (float*)w;                  // 2 MB  [j][k] fp32
    ushort_t* Cjm_r = (ushort_t*)(w + 2 * MB);    // 1 MB  [j][s]
    ushort_t* Cjm_i = (ushort_t*)(w + 3 * MB);    // 1 MB
    ushort_t* Csm_r = (ushort_t*)(w + 4 * MB);    // 1 MB  [s][j]
    ushort_t* Csm_i = (ushort_t*)(w + 5 * MB);    // 1 MB
    float*    dr    = (float*)(w + 6 * MB);       // 4 KB
    float*    di    = dr + DIM;                   // 4 KB
    float*    part  = (float*)(w + 7 * MB);       // 4 MB

    transpose_win_kernel<<<dim3(DIM / 64, SEQ / 64), 256, 0, stream>>>(W_in, WiT);
    circuit_wave64_kernel<<<SEQ + 1, 64, 0, stream>>>(WiT, b_in, qw, Cjm_r, Cjm_i, dr, di);
    transpose_c_kernel<<<dim3(SEQ / 64, DIM / 64), 256, 0, stream>>>(Cjm_r, Cjm_i, Csm_r, Csm_i);
    dim3 g2(NROWS / GBM, DIM / GBNC);
    gemm_fused_kernel<<<g2, 256, 0, stream>>>(x, Csm_r, Csm_i, dr, di, part);
    finalize_kernel<<<NROWS, 128, 0, stream>>>(part, W_out, b_out, out);
}